// Round 8
// baseline (116.935 us; speedup 1.0000x reference)
//
#include <hip/hip_runtime.h>

// NT-Xent loss, fused: never materialize the 8192x8192 similarity matrix.
// z = concat(z1,z2) [8192,256] f32 -> normalize -> bf16 zn (ws)
// S = zn @ zn^T via mfma_f32_32x32x16_bf16, fused per-row sum of exp(2*cos - 2)
// (fixed logsumexp max = 2: logits bounded by |cos|/T <= 2 -> partials additive)
// nll_r = -pos_r + 2 + log(sum_r); out = mean(nll)
//
// R8 = R7 with the compile fix (__exp2f -> __expf; HIP has no __exp2f):
// (a) 32x32x16 MFMA (17% fewer matrix-pipe cycles, half the issue slots);
// (b) ablation dispatches V1(no-epi)/V2(no-mfma)/V3(no-dma) at 1/4 length,
// writing to later-overwritten ws, to decompose the ~37% unattributed stall.

#define NHALF 4096
#define N2 8192
#define D 256
#define CSPLIT 16
#define RPB 128     // rows per block (4 waves x 32)
// per chunk: 16 phases x 32 cols = 512 cols

typedef __attribute__((ext_vector_type(8))) short short8;
typedef __attribute__((ext_vector_type(16))) float f32x16;
typedef __attribute__((ext_vector_type(4))) unsigned short u16x4;

__device__ __forceinline__ unsigned short f2bf(float f) {
  unsigned int u = __float_as_uint(f);
  unsigned int r = (u + 0x7fffu + ((u >> 16) & 1u)) >> 16;  // RNE
  return (unsigned short)r;
}

__device__ __forceinline__ void gload_lds16(const void* g, void* l) {
  __builtin_amdgcn_global_load_lds(
      (const __attribute__((address_space(1))) unsigned int*)g,
      (__attribute__((address_space(3))) unsigned int*)l, 16, 0, 0);
}

// ---------------- Kernel 1: row-normalize to bf16 ----------------
__global__ __launch_bounds__(256) void norm_kernel(const float* __restrict__ z1,
                                                   const float* __restrict__ z2,
                                                   short* __restrict__ zn) {
  const int lane = threadIdx.x & 63;
  const int row = blockIdx.x * 4 + (threadIdx.x >> 6);
  const float* src = (row < NHALF) ? (z1 + (size_t)row * D)
                                   : (z2 + (size_t)(row - NHALF) * D);
  const float4 v = *(const float4*)(src + lane * 4);
  float ss = v.x * v.x + v.y * v.y + v.z * v.z + v.w * v.w;
  #pragma unroll
  for (int m = 1; m < 64; m <<= 1) ss += __shfl_xor(ss, m);
  const float inv = 1.0f / fmaxf(sqrtf(ss), 1e-8f);
  u16x4 o;
  o[0] = f2bf(v.x * inv);
  o[1] = f2bf(v.y * inv);
  o[2] = f2bf(v.z * inv);
  o[3] = f2bf(v.w * inv);
  *(u16x4*)(zn + (size_t)row * D + lane * 4) = o;
}

// ---------------- Kernel 2: fused Gram + partial exp-sums ----------------
// grid (64 row-blocks, 16 col-chunks), 256 threads = 4 waves.
// Wave owns 32 rows; per phase computes one 32x32 output via 16x
// mfma_f32_32x32x16_bf16 (K=256). B staged to LDS (16KB/phase, dbuf) via
// global_load_lds with XOR-swizzle x^=((row&7)<<4) on global src AND ds_read.
// A/B lane l -> row/col (l&31), k = 8*(l>>5)+e (contig 16B)
// C/D lane l -> col (l&31), row = (g&3)+8*(g>>2)+4*(l>>5), g=0..15
// VAR: 0=real, 1=no-epilogue, 2=no-mfma, 3=no-dma (ablation; NPH=4)
template <int VAR, int NPH>
__global__ __launch_bounds__(256, 4) void simlse_t(const short* __restrict__ zn,
                                                   float* __restrict__ sum_ws,
                                                   float* __restrict__ pos_ws) {
  __shared__ __align__(16) char bsm[32768];
  const int lane = threadIdx.x & 63;
  const int wave = threadIdx.x >> 6;
  const int c31 = lane & 31;
  const int h2 = lane >> 5;
  const int rowbase = blockIdx.x * RPB + wave * 32;
  const int cc = blockIdx.y;

  // A fragments: 16 K-steps, 16B contiguous per lane.
  const short* ap = zn + (size_t)(rowbase + c31) * D + h2 * 8;
  short8 a[16];
  #pragma unroll
  for (int s = 0; s < 16; ++s) a[s] = *(const short8*)(ap + s * 16);
  #pragma unroll
  for (int s = 0; s < 16; ++s) asm volatile("" : "+v"(a[s]));

  float lsum[16];
  #pragma unroll
  for (int g = 0; g < 16; ++g) lsum[g] = 0.0f;

  const int dt32 = rowbase >> 5;                        // diagonal 32-col tile
  const int pt32 = ((rowbase + NHALF) & (N2 - 1)) >> 5; // positive-pair tile

  const char* znb = (const char*)zn;
  // Stage 32 cols (16 KB) into LDS half. LDS[y] = zn[(colbase+(y>>9))*512 +
  // ((y&511) ^ ((row&7)<<4))]; XOR involution matches the ds_read below.
  auto stage = [&](int half, int ph) {
    const int colbase = cc * 512 + ph * 32;
    #pragma unroll
    for (int s = 0; s < 4; ++s) {
      const int y = s * 4096 + wave * 1024 + lane * 16;
      const int row = y >> 9;
      const int off = (y & 511) ^ ((row & 7) << 4);
      const void* gp = znb + (size_t)(colbase + row) * 512 + off;
      void* lp = bsm + half * 16384 + s * 4096 + wave * 1024;  // +lane*16 by HW
      gload_lds16(gp, lp);
    }
  };

  const int rbyte = c31 * 512;
  const int sw = (c31 & 7) << 4;
  const int hi16 = h2 * 16;

  stage(0, 0);
  __syncthreads();
  for (int ph = 0; ph < NPH; ++ph) {
    if (ph + 1 < NPH && VAR != 3) stage((ph + 1) & 1, ph + 1);
    const char* tb = bsm + (ph & 1) * 16384;
    const int ct32 = cc * 16 + ph;
    f32x16 acc = {0.f, 0.f, 0.f, 0.f, 0.f, 0.f, 0.f, 0.f,
                  0.f, 0.f, 0.f, 0.f, 0.f, 0.f, 0.f, 0.f};
    if (VAR != 2) {
      #pragma unroll
      for (int s = 0; s < 16; ++s) {
        const short8 b = *(const short8*)(tb + rbyte + ((s * 32 + hi16) ^ sw));
        acc = __builtin_amdgcn_mfma_f32_32x32x16_bf16(a[s], b, acc, 0, 0, 0);
      }
    } else {
      #pragma unroll
      for (int s = 0; s < 16; ++s) {
        short8 b = *(const short8*)(tb + rbyte + ((s * 32 + hi16) ^ sw));
        asm volatile("" :: "v"(b));  // keep ds_read live (rule #17)
      }
    }
    if (VAR == 0 || VAR == 3) {
      const bool isd = (ct32 == dt32);
      const bool isp = (ct32 == pt32);
      if (!isd && !isp) {
        #pragma unroll
        for (int g = 0; g < 16; ++g)
          lsum[g] += __expf(fmaf(acc[g], 2.0f, -2.0f));
      } else {
        #pragma unroll
        for (int g = 0; g < 16; ++g) {
          const int rl = (g & 3) + 8 * (g >> 2) + 4 * h2;  // local row 0..31
          const bool hit = (c31 == rl);                    // tile diagonal
          float e = __expf(fmaf(acc[g], 2.0f, -2.0f));
          if (isd && hit) e = 0.0f;                        // mask self-sim
          if (isp && hit) pos_ws[rowbase + rl] = acc[g] * 2.0f;
          lsum[g] += e;
        }
      }
    } else if (VAR == 1) {
      #pragma unroll
      for (int g = 0; g < 16; ++g) asm volatile("" :: "v"(acc[g]));
    }
    __syncthreads();
  }

  // Reduce exp-sums across each 32-lane column group.
  #pragma unroll
  for (int g = 0; g < 16; ++g) {
    #pragma unroll
    for (int m = 1; m < 32; m <<= 1) lsum[g] += __shfl_xor(lsum[g], m);
  }
  if (c31 == 0) {
    #pragma unroll
    for (int g = 0; g < 16; ++g) {
      const int rl = (g & 3) + 8 * (g >> 2) + 4 * h2;
      sum_ws[(size_t)(rowbase + rl) * CSPLIT + cc] = lsum[g];
    }
  }
}

// ---------------- Kernel 3a: per-row nll + per-block partial sum ----------------
__global__ __launch_bounds__(256) void nll_kernel(const float* __restrict__ sum_ws,
                                                  const float* __restrict__ pos_ws,
                                                  float* __restrict__ partial) {
  const int r = blockIdx.x * 256 + threadIdx.x;
  const float4* sp = (const float4*)(sum_ws + (size_t)r * CSPLIT);
  float t = 0.0f;
  #pragma unroll
  for (int i = 0; i < CSPLIT / 4; ++i) {
    const float4 v = sp[i];
    t += v.x + v.y + v.z + v.w;
  }
  float nll = -pos_ws[r] + 2.0f + __logf(t);
  #pragma unroll
  for (int m = 1; m < 64; m <<= 1) nll += __shfl_xor(nll, m);
  __shared__ float red[4];
  const int lane = threadIdx.x & 63;
  const int wave = threadIdx.x >> 6;
  if (lane == 0) red[wave] = nll;
  __syncthreads();
  if (threadIdx.x == 0) partial[blockIdx.x] = red[0] + red[1] + red[2] + red[3];
}

// ---------------- Kernel 3b: final mean ----------------
__global__ __launch_bounds__(64) void final_kernel(const float* __restrict__ partial,
                                                   float* __restrict__ out) {
  const int lane = threadIdx.x;
  float v = (lane < 32) ? partial[lane] : 0.0f;
  #pragma unroll
  for (int m = 1; m < 64; m <<= 1) v += __shfl_xor(v, m);
  if (lane == 0) out[0] = v * (1.0f / (float)N2);
}

extern "C" void kernel_launch(void* const* d_in, const int* in_sizes, int n_in,
                              void* d_out, int out_size, void* d_ws, size_t ws_size,
                              hipStream_t stream) {
  const float* z1 = (const float*)d_in[0];
  const float* z2 = (const float*)d_in[1];
  float* out = (float*)d_out;

  char* ws = (char*)d_ws;
  short* zn = (short*)ws;                                   // 8192*256*2 = 4 MB
  float* sum_ws = (float*)(ws + (size_t)N2 * D * 2);        // 8192*16*4 = 512 KB
  float* pos_ws = sum_ws + (size_t)N2 * CSPLIT;             // 8192*4 = 32 KB
  float* partial = pos_ws + N2;                             // 32 floats

  hipLaunchKernelGGL(norm_kernel, dim3(N2 / 4), dim3(256), 0, stream, z1, z2, zn);
  // Ablation probes (1/4 length, outputs overwritten by the real pass below).
  hipLaunchKernelGGL((simlse_t<1, 4>), dim3(N2 / RPB, CSPLIT), dim3(256), 0, stream,
                     zn, sum_ws, pos_ws);
  hipLaunchKernelGGL((simlse_t<2, 4>), dim3(N2 / RPB, CSPLIT), dim3(256), 0, stream,
                     zn, sum_ws, pos_ws);
  hipLaunchKernelGGL((simlse_t<3, 4>), dim3(N2 / RPB, CSPLIT), dim3(256), 0, stream,
                     zn, sum_ws, pos_ws);
  // Real pass.
  hipLaunchKernelGGL((simlse_t<0, 16>), dim3(N2 / RPB, CSPLIT), dim3(256), 0, stream,
                     zn, sum_ws, pos_ws);
  hipLaunchKernelGGL(nll_kernel, dim3(N2 / 256), dim3(256), 0, stream, sum_ws, pos_ws, partial);
  hipLaunchKernelGGL(final_kernel, dim3(1), dim3(64), 0, stream, partial, out);
}

// Round 9
// 58.644 us; speedup vs baseline: 1.9940x; 1.9940x over previous
//
#include <hip/hip_runtime.h>

// NT-Xent loss, fused: never materialize the 8192x8192 similarity matrix.
// z = concat(z1,z2) [8192,256] f32 -> normalize -> bf16 zn (ws)
// S = zn @ zn^T via mfma_f32_32x32x16_bf16, fused per-row sum of exp(2*cos - 2)
// (fixed logsumexp max = 2: logits bounded by |cos|/T <= 2 -> partials additive)
// nll_r = -pos_r + 2 + log(sum_r); out = mean(nll)
//
// R9: 64 rows/wave (two 32-row stripes sharing each B-fragment read -> LDS
// read volume halves to 8 B/output elem, off the critical path) under
// __launch_bounds__(256,2) (VGPR cap 256; R8 spilled at cap 128: WRITE_SIZE
// 17 MB). Grid 32x16 = 512 blocks = exactly 2/CU, no tail. No ablations.

#define NHALF 4096
#define N2 8192
#define D 256
#define CSPLIT 16
#define NPH 16      // phases per chunk; 32 cols per phase
#define RPB 256     // rows per block (4 waves x 64)

typedef __attribute__((ext_vector_type(8))) short short8;
typedef __attribute__((ext_vector_type(16))) float f32x16;
typedef __attribute__((ext_vector_type(4))) unsigned short u16x4;

__device__ __forceinline__ unsigned short f2bf(float f) {
  unsigned int u = __float_as_uint(f);
  unsigned int r = (u + 0x7fffu + ((u >> 16) & 1u)) >> 16;  // RNE
  return (unsigned short)r;
}

__device__ __forceinline__ void gload_lds16(const void* g, void* l) {
  __builtin_amdgcn_global_load_lds(
      (const __attribute__((address_space(1))) unsigned int*)g,
      (__attribute__((address_space(3))) unsigned int*)l, 16, 0, 0);
}

// ---------------- Kernel 1: row-normalize to bf16 ----------------
__global__ __launch_bounds__(256) void norm_kernel(const float* __restrict__ z1,
                                                   const float* __restrict__ z2,
                                                   short* __restrict__ zn) {
  const int lane = threadIdx.x & 63;
  const int row = blockIdx.x * 4 + (threadIdx.x >> 6);
  const float* src = (row < NHALF) ? (z1 + (size_t)row * D)
                                   : (z2 + (size_t)(row - NHALF) * D);
  const float4 v = *(const float4*)(src + lane * 4);
  float ss = v.x * v.x + v.y * v.y + v.z * v.z + v.w * v.w;
  #pragma unroll
  for (int m = 1; m < 64; m <<= 1) ss += __shfl_xor(ss, m);
  const float inv = 1.0f / fmaxf(sqrtf(ss), 1e-8f);
  u16x4 o;
  o[0] = f2bf(v.x * inv);
  o[1] = f2bf(v.y * inv);
  o[2] = f2bf(v.z * inv);
  o[3] = f2bf(v.w * inv);
  *(u16x4*)(zn + (size_t)row * D + lane * 4) = o;
}

// ---------------- Kernel 2: fused Gram + partial exp-sums ----------------
// grid (32 row-blocks, 16 col-chunks), 256 threads = 4 waves.
// Wave owns 64 rows = 2 stripes of 32; per phase computes two 32x32 outputs
// via 2x16 mfma_f32_32x32x16_bf16 (K=256), sharing each B-fragment read.
// B staged to LDS (16KB/phase, dbuf) via global_load_lds, XOR-swizzle
// x^=((row&7)<<4) on global src AND ds_read (rule #21).
// A/B lane l -> row/col (l&31), k = 8*(l>>5)+e (contig 16B)
// C/D lane l -> col (l&31), row = (g&3)+8*(g>>2)+4*(l>>5), g=0..15
__global__ __launch_bounds__(256, 2) void simlse_kernel(const short* __restrict__ zn,
                                                        float* __restrict__ sum_ws,
                                                        float* __restrict__ pos_ws) {
  __shared__ __align__(16) char bsm[32768];
  const int lane = threadIdx.x & 63;
  const int wave = threadIdx.x >> 6;
  const int c31 = lane & 31;
  const int h2 = lane >> 5;
  const int rowbase = blockIdx.x * RPB + wave * 64;
  const int cc = blockIdx.y;

  // A fragments: 2 stripes x 16 K-steps, 16B contiguous per lane (128 VGPR).
  short8 a[2][16];
  #pragma unroll
  for (int st = 0; st < 2; ++st) {
    const short* ap = zn + (size_t)(rowbase + st * 32 + c31) * D + h2 * 8;
    #pragma unroll
    for (int s = 0; s < 16; ++s) a[st][s] = *(const short8*)(ap + s * 16);
  }
  #pragma unroll
  for (int st = 0; st < 2; ++st)
    #pragma unroll
    for (int s = 0; s < 16; ++s) asm volatile("" : "+v"(a[st][s]));

  float lsum[2][16];
  #pragma unroll
  for (int st = 0; st < 2; ++st)
    #pragma unroll
    for (int g = 0; g < 16; ++g) lsum[st][g] = 0.0f;

  int dt[2], pt[2];
  #pragma unroll
  for (int st = 0; st < 2; ++st) {
    dt[st] = (rowbase + st * 32) >> 5;                        // diagonal tile
    pt[st] = ((rowbase + st * 32 + NHALF) & (N2 - 1)) >> 5;   // positive tile
  }

  const char* znb = (const char*)zn;
  // Stage 32 cols (16 KB) into LDS half. LDS[y] = zn[(colbase+(y>>9))*512 +
  // ((y&511) ^ ((row&7)<<4))]; XOR involution matches the ds_read below.
  auto stage = [&](int half, int ph) {
    const int colbase = cc * 512 + ph * 32;
    #pragma unroll
    for (int s = 0; s < 4; ++s) {
      const int y = s * 4096 + wave * 1024 + lane * 16;
      const int row = y >> 9;
      const int off = (y & 511) ^ ((row & 7) << 4);
      const void* gp = znb + (size_t)(colbase + row) * 512 + off;
      void* lp = bsm + half * 16384 + s * 4096 + wave * 1024;  // +lane*16 by HW
      gload_lds16(gp, lp);
    }
  };

  const int rbyte = c31 * 512;
  const int sw = (c31 & 7) << 4;
  const int hi16 = h2 * 16;

  stage(0, 0);
  __syncthreads();
  for (int ph = 0; ph < NPH; ++ph) {
    if (ph + 1 < NPH) stage((ph + 1) & 1, ph + 1);  // DMA overlaps compute
    const char* tb = bsm + (ph & 1) * 16384;
    const int ct32 = cc * 16 + ph;
    f32x16 acc0 = {0.f, 0.f, 0.f, 0.f, 0.f, 0.f, 0.f, 0.f,
                   0.f, 0.f, 0.f, 0.f, 0.f, 0.f, 0.f, 0.f};
    f32x16 acc1 = acc0;
    #pragma unroll
    for (int s = 0; s < 16; ++s) {
      const short8 b = *(const short8*)(tb + rbyte + ((s * 32 + hi16) ^ sw));
      acc0 = __builtin_amdgcn_mfma_f32_32x32x16_bf16(a[0][s], b, acc0, 0, 0, 0);
      acc1 = __builtin_amdgcn_mfma_f32_32x32x16_bf16(a[1][s], b, acc1, 0, 0, 0);
    }
    #pragma unroll
    for (int st = 0; st < 2; ++st) {
      const f32x16& acc = st ? acc1 : acc0;
      const bool isd = (ct32 == dt[st]);
      const bool isp = (ct32 == pt[st]);
      if (!isd && !isp) {
        #pragma unroll
        for (int g = 0; g < 16; ++g)
          lsum[st][g] += __expf(fmaf(acc[g], 2.0f, -2.0f));
      } else {
        #pragma unroll
        for (int g = 0; g < 16; ++g) {
          const int rl = (g & 3) + 8 * (g >> 2) + 4 * h2;  // local row 0..31
          const bool hit = (c31 == rl);                    // tile diagonal
          float e = __expf(fmaf(acc[g], 2.0f, -2.0f));
          if (isd && hit) e = 0.0f;                        // mask self-sim
          if (isp && hit) pos_ws[rowbase + st * 32 + rl] = acc[g] * 2.0f;
          lsum[st][g] += e;
        }
      }
    }
    __syncthreads();
  }

  // Reduce exp-sums across each 32-lane column group.
  #pragma unroll
  for (int st = 0; st < 2; ++st)
    #pragma unroll
    for (int g = 0; g < 16; ++g) {
      #pragma unroll
      for (int m = 1; m < 32; m <<= 1)
        lsum[st][g] += __shfl_xor(lsum[st][g], m);
    }
  if (c31 == 0) {
    #pragma unroll
    for (int st = 0; st < 2; ++st)
      #pragma unroll
      for (int g = 0; g < 16; ++g) {
        const int rl = (g & 3) + 8 * (g >> 2) + 4 * h2;
        sum_ws[(size_t)(rowbase + st * 32 + rl) * CSPLIT + cc] = lsum[st][g];
      }
  }
}

// ---------------- Kernel 3a: per-row nll + per-block partial sum ----------------
__global__ __launch_bounds__(256) void nll_kernel(const float* __restrict__ sum_ws,
                                                  const float* __restrict__ pos_ws,
                                                  float* __restrict__ partial) {
  const int r = blockIdx.x * 256 + threadIdx.x;
  const float4* sp = (const float4*)(sum_ws + (size_t)r * CSPLIT);
  float t = 0.0f;
  #pragma unroll
  for (int i = 0; i < CSPLIT / 4; ++i) {
    const float4 v = sp[i];
    t += v.x + v.y + v.z + v.w;
  }
  float nll = -pos_ws[r] + 2.0f + __logf(t);
  #pragma unroll
  for (int m = 1; m < 64; m <<= 1) nll += __shfl_xor(nll, m);
  __shared__ float red[4];
  const int lane = threadIdx.x & 63;
  const int wave = threadIdx.x >> 6;
  if (lane == 0) red[wave] = nll;
  __syncthreads();
  if (threadIdx.x == 0) partial[blockIdx.x] = red[0] + red[1] + red[2] + red[3];
}

// ---------------- Kernel 3b: final mean ----------------
__global__ __launch_bounds__(64) void final_kernel(const float* __restrict__ partial,
                                                   float* __restrict__ out) {
  const int lane = threadIdx.x;
  float v = (lane < 32) ? partial[lane] : 0.0f;
  #pragma unroll
  for (int m = 1; m < 64; m <<= 1) v += __shfl_xor(v, m);
  if (lane == 0) out[0] = v * (1.0f / (float)N2);
}

extern "C" void kernel_launch(void* const* d_in, const int* in_sizes, int n_in,
                              void* d_out, int out_size, void* d_ws, size_t ws_size,
                              hipStream_t stream) {
  const float* z1 = (const float*)d_in[0];
  const float* z2 = (const float*)d_in[1];
  float* out = (float*)d_out;

  char* ws = (char*)d_ws;
  short* zn = (short*)ws;                                   // 8192*256*2 = 4 MB
  float* sum_ws = (float*)(ws + (size_t)N2 * D * 2);        // 8192*16*4 = 512 KB
  float* pos_ws = sum_ws + (size_t)N2 * CSPLIT;             // 8192*4 = 32 KB
  float* partial = pos_ws + N2;                             // 32 floats

  hipLaunchKernelGGL(norm_kernel, dim3(N2 / 4), dim3(256), 0, stream, z1, z2, zn);
  hipLaunchKernelGGL(simlse_kernel, dim3(N2 / RPB, CSPLIT), dim3(256), 0, stream,
                     zn, sum_ws, pos_ws);
  hipLaunchKernelGGL(nll_kernel, dim3(N2 / 256), dim3(256), 0, stream, sum_ws, pos_ws, partial);
  hipLaunchKernelGGL(final_kernel, dim3(1), dim3(64), 0, stream, partial, out);
}